// Round 9
// baseline (138.491 us; speedup 1.0000x reference)
//
#include <hip/hip_runtime.h>
#include <math.h>

#define BB 8
#define TT 1200
#define NFFT 1024
#define BINS 513
#define LTOT 307200
#define KREV 8192
#define NFRM 34
#define NSAMP 8960
#define OUTOFF 299008          // LTOT - KREV
#define SQRT_SR 154.91933384829668f

// workspace layout (floats)
#define OFF_FR   0             // 8*34*1024 istft frames (windowed)

// LDS bank-conflict swizzle for 1024-float FFT arrays; bijective on [0,1024).
#define PHI(i) ((i) ^ ((i) >> 5))

typedef float f2 __attribute__((ext_vector_type(2)));

// packed fp32 FMA: acc.lo += b.lo*c.lo; acc.hi += b.hi*c.hi  (VOP3P, 2x fp32 rate)
#define PK(A, B, C) asm("v_pk_fma_f32 %0, %1, %2, %0" : "+v"(A) : "v"(B), "v"(C))

// base-4 digit reversal of a 10-bit index (bit-reverse, then swap adjacent bits)
__device__ __forceinline__ int rev4_10(int n) {
    int r = (int)(__brev((unsigned)n) >> 22);
    return ((r & 0x155) << 1) | ((r & 0x2AA) >> 1);
}

// radix-4 DIF, 1024 pts: input natural, output at position p = X[rev4(p)].
__device__ __forceinline__ void dif4(float* re, float* im,
                                     const float* twr, const float* twi,
                                     float dir, int u, bool act) {
#pragma unroll
    for (int s = 0; s < 5; ++s) {
        const int q = 256 >> (2 * s);
        const int sh = 8 - 2 * s;
        if (s < 2) __syncthreads();
        else       asm volatile("s_waitcnt lgkmcnt(0)" ::: "memory");
        if (act) {
            int t = u & (q - 1);
            int base = ((u >> sh) << (sh + 2)) | t;
            int i0 = PHI(base), i1 = PHI(base + q), i2 = PHI(base + 2 * q), i3 = PHI(base + 3 * q);
            float ar = re[i0], ai = im[i0];
            float br = re[i1], bi = im[i1];
            float cr = re[i2], ci = im[i2];
            float dr = re[i3], di = im[i3];
            float t0r = ar + cr, t0i = ai + ci;
            float t1r = ar - cr, t1i = ai - ci;
            float t2r = br + dr, t2i = bi + di;
            float t3r = br - dr, t3i = bi - di;
            float y0r = t0r + t2r, y0i = t0i + t2i;
            float y2r = t0r - t2r, y2i = t0i - t2i;
            float y1r = t1r - dir * t3i, y1i = t1i + dir * t3r;
            float y3r = t1r + dir * t3i, y3i = t1i - dir * t3r;
            float c1 = twr[2 * q - 1 + t], s1 = twi[2 * q - 1 + t];
            float c2 = twr[q - 1 + t],     s2 = twi[q - 1 + t];
            float w1r = c1, w1i = dir * s1;
            float w2r = c2, w2i = dir * s2;
            float w3r = c1 * c2 - s1 * s2;
            float w3i = dir * (c1 * s2 + s1 * c2);
            re[i0] = y0r;                       im[i0] = y0i;
            re[i1] = y1r * w1r - y1i * w1i;     im[i1] = y1r * w1i + y1i * w1r;
            re[i2] = y2r * w2r - y2i * w2i;     im[i2] = y2r * w2i + y2i * w2r;
            re[i3] = y3r * w3r - y3i * w3i;     im[i3] = y3r * w3i + y3i * w3r;
        }
    }
    __syncthreads();
}

// radix-4 DIT, 1024 pts: input at position p = x[rev4(p)], output natural.
__device__ __forceinline__ void dit4(float* re, float* im,
                                     const float* twr, const float* twi,
                                     float dir, int u, bool act) {
#pragma unroll
    for (int s = 0; s < 5; ++s) {
        const int q = 1 << (2 * s);
        const int sh = 2 * s;
        if (s == 0 || s == 4) __syncthreads();
        else                  asm volatile("s_waitcnt lgkmcnt(0)" ::: "memory");
        if (act) {
            int t = u & (q - 1);
            int base = ((u >> sh) << (sh + 2)) | t;
            int i0 = PHI(base), i1 = PHI(base + q), i2 = PHI(base + 2 * q), i3 = PHI(base + 3 * q);
            float c1 = twr[2 * q - 1 + t], s1 = twi[2 * q - 1 + t];
            float c2 = twr[q - 1 + t],     s2 = twi[q - 1 + t];
            float w1r = c1, w1i = dir * s1;
            float w2r = c2, w2i = dir * s2;
            float w3r = c1 * c2 - s1 * s2;
            float w3i = dir * (c1 * s2 + s1 * c2);
            float ar = re[i0], ai = im[i0];
            float xr = re[i1], xi = im[i1];
            float yr = re[i2], yi = im[i2];
            float zr = re[i3], zi = im[i3];
            float br = xr * w1r - xi * w1i, bi = xr * w1i + xi * w1r;
            float cr = yr * w2r - yi * w2i, ci = yr * w2i + yi * w2r;
            float dr = zr * w3r - zi * w3i, di = zr * w3i + zi * w3r;
            float t0r = ar + cr, t0i = ai + ci;
            float t1r = ar - cr, t1i = ai - ci;
            float t2r = br + dr, t2i = bi + di;
            float t3r = br - dr, t3i = bi - di;
            re[i0] = t0r + t2r;            im[i0] = t0i + t2i;
            re[i2] = t0r - t2r;            im[i2] = t0i - t2i;
            re[i1] = t1r - dir * t3i;      im[i1] = t1i + dir * t3r;
            re[i3] = t1r + dir * t3i;      im[i3] = t1i - dir * t3r;
        }
    }
    __syncthreads();
}

// tree-scan level offsets within L
#define LV1 0
#define LV2 4480
#define LV3 6720
#define LV4 7840
#define LV5 8400
#define LV6 8680
#define LV7 8820
#define LV8 8890
#define LV9 8925
#define LV10 8942
#define LV11 8950
#define LV12 8954
#define LV13 8956

// KFRM: round-1 configuration verbatim (pinned at ~42.8 us across 6 structural
// variants; untouched).
__global__ __launch_bounds__(512) void kfrm(const float* __restrict__ f0,
                                            const float* __restrict__ env_per,
                                            const float* __restrict__ env_noi,
                                            const float* __restrict__ noi,
                                            const float* __restrict__ win,
                                            float* __restrict__ W,
                                            float* __restrict__ out) {
    const int bid = blockIdx.x;           // 0..135
    const int tid = threadIdx.x;
    const int b = bid / 17;
    const int fp = (bid - b * 17) * 2;    // f = fp, g = fp+1
    const int fg = fp + 1;

    __shared__ __align__(16) float SMEM[17917];   // union: {F[8960],L[8957]} | FFT arrays
    __shared__ float cw[1281], fw[1281];
    __shared__ float twr[1023], twi[1023];

    // ---- early prefetch of every scattered global read
    const int idxF = (fp > 0) ? (fp - 1) : 0;
    const int idxG = fg - 1;
    float pfEpF = 0.f, pfEpG = 0.f, pfEpF2 = 0.f, pfEpG2 = 0.f;
    {
        pfEpF = env_per[((size_t)(b * BINS + tid)) * TT + idxF];
        pfEpG = env_per[((size_t)(b * BINS + tid)) * TT + idxG];
        if (tid == 0) {
            pfEpF2 = env_per[((size_t)(b * BINS + 512)) * TT + idxF];
            pfEpG2 = env_per[((size_t)(b * BINS + 512)) * TT + idxG];
        }
    }
    const float pfF0F = f0[b * TT + idxF];
    const float pfF0G = f0[b * TT + idxG];
    int ktmp0 = rev4_10(tid);
    const int kk0 = (ktmp0 <= 512) ? ktmp0 : 1024 - ktmp0;
    int ktmp1 = rev4_10(tid + 512);
    const int kk1 = (ktmp1 <= 512) ? ktmp1 : 1024 - ktmp1;
    const float pfEnF0 = env_noi[((size_t)(b * BINS + kk0)) * TT + idxF];
    const float pfEnG0 = env_noi[((size_t)(b * BINS + kk0)) * TT + idxG];
    const float pfEnF1 = env_noi[((size_t)(b * BINS + kk1)) * TT + idxF];
    const float pfEnG1 = env_noi[((size_t)(b * BINS + kk1)) * TT + idxG];
    int iF0 = 256 * fp + tid - 512; if (iF0 < 0) iF0 = -iF0;
    const int iF1 = 256 * fp + tid;
    int iG0 = 256 * fg + tid - 512; if (iG0 < 0) iG0 = -iG0;
    const int iG1 = 256 * fg + tid;
    const float pfNoiF0 = noi[(size_t)b * LTOT + iF0];
    const float pfNoiF1 = noi[(size_t)b * LTOT + iF1];
    const float pfNoiG0 = noi[(size_t)b * LTOT + iG0];
    const float pfNoiG1 = noi[(size_t)b * LTOT + iG1];
    const float pfWin0 = win[tid];
    const float pfWin1 = win[tid + 512];

    // ---- phase 0: zero-fill out (grid-stride), twiddles
    {
        float4* out4 = (float4*)out;
        int g = bid * 512 + tid;
        for (int idx = g; idx < (BB * LTOT) / 4; idx += 136 * 512)
            out4[idx] = make_float4(0.f, 0.f, 0.f, 0.f);
    }
    for (int x = tid; x < 1023; x += 512) {
        int hb = 31 - __clz(x + 1);
        int half = 1 << hb;
        int t = (x + 1) - half;
        float a = 3.14159265358979323846f * ((float)t / (float)half);
        float sv, cv; sincosf(a, &sv, &cv);
        twr[x] = cv; twi[x] = sv;
    }

    // ---- phase 1: bit-exact f0 upsample + tree cumsum (merged levels)
    float* F = SMEM;            // 8960
    float* L = SMEM + 8960;     // 8957
    for (int i = tid; i < NSAMP; i += 512) {
        float src = __fsub_rn(__fdiv_rn(__fadd_rn((float)i, 0.5f), 256.0f), 0.5f);
        src = fminf(fmaxf(src, 0.0f), (float)(TT - 1));
        int i0 = (int)floorf(src);
        int i1 = i0 + 1; if (i1 > TT - 1) i1 = TT - 1;
        float w = __fsub_rn(src, (float)i0);
        float a0 = __fmul_rn(f0[b * TT + i0], __fsub_rn(1.0f, w));
        float a1 = __fmul_rn(f0[b * TT + i1], w);
        F[i] = __fadd_rn(a0, a1);
    }
    __syncthreads();
    for (int j = tid; j < 2240; j += 512) {           // levels 1+2
        float a = __fadd_rn(F[4*j],     F[4*j + 1]);
        float c = __fadd_rn(F[4*j + 2], F[4*j + 3]);
        L[LV1 + 2*j] = a; L[LV1 + 2*j + 1] = c;
        L[LV2 + j] = __fadd_rn(a, c);
    }
    __syncthreads();
    for (int j = tid; j < 560; j += 512) {            // levels 3+4
        float a = __fadd_rn(L[LV2 + 4*j],     L[LV2 + 4*j + 1]);
        float c = __fadd_rn(L[LV2 + 4*j + 2], L[LV2 + 4*j + 3]);
        L[LV3 + 2*j] = a; L[LV3 + 2*j + 1] = c;
        L[LV4 + j] = __fadd_rn(a, c);
    }
    __syncthreads();
    if (tid < 140) {                                  // levels 5+6
        int j = tid;
        float a = __fadd_rn(L[LV4 + 4*j],     L[LV4 + 4*j + 1]);
        float c = __fadd_rn(L[LV4 + 4*j + 2], L[LV4 + 4*j + 3]);
        L[LV5 + 2*j] = a; L[LV5 + 2*j + 1] = c;
        L[LV6 + j] = __fadd_rn(a, c);
    }
    __syncthreads();
    if (tid < 35) {                                   // levels 7+8
        int j = tid;
        float a = __fadd_rn(L[LV6 + 4*j],     L[LV6 + 4*j + 1]);
        float c = __fadd_rn(L[LV6 + 4*j + 2], L[LV6 + 4*j + 3]);
        L[LV7 + 2*j] = a; L[LV7 + 2*j + 1] = c;
        L[LV8 + j] = __fadd_rn(a, c);
    }
    __syncthreads();
    if (tid < 9) {                                    // levels 9+10 (L9 has 17 nodes)
        int j = tid;
        if (j < 8) {
            float a = __fadd_rn(L[LV8 + 4*j],     L[LV8 + 4*j + 1]);
            float c = __fadd_rn(L[LV8 + 4*j + 2], L[LV8 + 4*j + 3]);
            L[LV9 + 2*j] = a; L[LV9 + 2*j + 1] = c;
            L[LV10 + j] = __fadd_rn(a, c);
        } else {
            L[LV9 + 16] = __fadd_rn(L[LV8 + 32], L[LV8 + 33]);
        }
    }
    __syncthreads();
    if (tid == 0) {                                   // levels 11..13
        float a0 = __fadd_rn(L[LV10 + 0], L[LV10 + 1]);
        float a1 = __fadd_rn(L[LV10 + 2], L[LV10 + 3]);
        float a2 = __fadd_rn(L[LV10 + 4], L[LV10 + 5]);
        float a3 = __fadd_rn(L[LV10 + 6], L[LV10 + 7]);
        L[LV11 + 0] = a0; L[LV11 + 1] = a1; L[LV11 + 2] = a2; L[LV11 + 3] = a3;
        float b0 = __fadd_rn(a0, a1), b1 = __fadd_rn(a2, a3);
        L[LV12 + 0] = b0; L[LV12 + 1] = b1;
        L[LV13 + 0] = __fadd_rn(b0, b1);
    }
    __syncthreads();
    const int cbase = (fp >= 3) ? (256 * fp - 513) : 0;
    {
        const int offs[14] = {0, LV1, LV2, LV3, LV4, LV5, LV6, LV7, LV8, LV9, LV10, LV11, LV12, LV13};
        for (int w = tid; w < 1281; w += 512) {
            int p = cbase + w;
            if (p < NSAMP) {
                int n = p + 1;
                float acc = 0.f; int pos = 0; bool first = true;
#pragma unroll
                for (int k = 13; k >= 1; --k) {
                    if ((n >> k) & 1) {
                        float t = L[offs[k] + (pos >> k)];
                        acc = first ? t : __fadd_rn(acc, t);
                        first = false;
                        pos += (1 << k);
                    }
                }
                if (n & 1) {
                    float t = F[pos];
                    acc = first ? t : __fadd_rn(acc, t);
                }
                cw[w] = acc;
                fw[w] = F[p];
            }
        }
    }
    __syncthreads();

    // ---- phase 2: FFT pipeline (union reused)
    float* wr_  = SMEM;          // 1024
    float* wi_  = SMEM + 1024;
    float* zfr  = SMEM + 2048;
    float* zfi  = SMEM + 3072;
    float* zgr  = SMEM + 4096;
    float* zgi  = SMEM + 5120;
    float* mpfr = SMEM + 6144;   // 513 each
    float* mpfi = SMEM + 6660;
    float* mpgr = SMEM + 7176;
    float* mpgi = SMEM + 7692;
    const int u = tid & 255;
    const bool lo = (tid < 256);

    {
        const bool gF = (fp > 0) && (pfF0F > 20.0f);
        const bool gG = (pfF0G > 20.0f);
        mpfr[tid] = logf(fmaxf(gF ? pfEpF : 0.0f, 1e-5f));
        mpgr[tid] = logf(fmaxf(gG ? pfEpG : 0.0f, 1e-5f));
        if (tid == 0) {
            mpfr[512] = logf(fmaxf(gF ? pfEpF2 : 0.0f, 1e-5f));
            mpgr[512] = logf(fmaxf(gG ? pfEpG2 : 0.0f, 1e-5f));
        }
    }
    __syncthreads();
#pragma unroll
    for (int r = 0; r < 2; ++r) {
        int n = tid + 512 * r;
        int kv = (n <= 512) ? n : 1024 - n;
        wr_[PHI(n)] = mpfr[kv];
        wi_[PHI(n)] = mpgr[kv];
    }
    dif4(wr_, wi_, twr, twi, -1.f, u, lo);
    const float inv = 1.0f / 1024.0f;
#pragma unroll
    for (int r = 0; r < 2; ++r) {
        int p = tid + 512 * r;
        int n = rev4_10(p);
        float wgt = (n == 0 || n == 512) ? inv : ((n < 512) ? 2.0f * inv : 0.0f);
        wr_[PHI(p)] *= wgt;
        wi_[PHI(p)] *= wgt;
    }
    dit4(wr_, wi_, twr, twi, -1.f, u, lo);      // Y natural
    for (int k = tid; k < BINS; k += 512) {
        int mk = (1024 - k) & 1023;
        float yr = wr_[PHI(k)], yi = wi_[PHI(k)];
        float ymr = wr_[PHI(mk)], ymi = -wi_[PHI(mk)];
        float Lfr = 0.5f * (yr + ymr), Lfi = 0.5f * (yi + ymi);
        float dr = yr - ymr, di = yi - ymi;
        float Lgr = 0.5f * di, Lgi = -0.5f * dr;
        float ef = expf(Lfr);
        mpfr[k] = ef * cosf(Lfi); mpfi[k] = ef * sinf(Lfi);
        float eg = expf(Lgr);
        mpgr[k] = eg * cosf(Lgi); mpgi[k] = eg * sinf(Lgi);
    }
    __syncthreads();
    {
        {
            const int n = tid;
            float v = 0.0f;
            int i = iF0;
            if (i > 0) {
                int iw = i - cbase;
                float ph  = __fdiv_rn(cw[iw], 24000.0f);
                float sw  = __fsub_rn(ph, floorf(ph));
                float ph2 = __fdiv_rn(cw[iw - 1], 24000.0f);
                float sw2 = __fsub_rn(ph2, floorf(ph2));
                if (__fsub_rn(sw, sw2) < 0.0f)
                    v = __fmul_rn(__fdiv_rn(1.0f, __fsqrt_rn(fmaxf(fw[iw], 20.0f))), SQRT_SR);
            }
            zfr[PHI(n)] = __fmul_rn(pfNoiF0, pfWin0);
            zfi[PHI(n)] = __fmul_rn(v, pfWin0);
            float v2 = 0.0f;
            int i2 = iG0;
            if (i2 > 0) {
                int iw = i2 - cbase;
                float ph  = __fdiv_rn(cw[iw], 24000.0f);
                float sw  = __fsub_rn(ph, floorf(ph));
                float ph2 = __fdiv_rn(cw[iw - 1], 24000.0f);
                float sw2 = __fsub_rn(ph2, floorf(ph2));
                if (__fsub_rn(sw, sw2) < 0.0f)
                    v2 = __fmul_rn(__fdiv_rn(1.0f, __fsqrt_rn(fmaxf(fw[iw], 20.0f))), SQRT_SR);
            }
            zgr[PHI(n)] = __fmul_rn(pfNoiG0, pfWin0);
            zgi[PHI(n)] = __fmul_rn(v2, pfWin0);
        }
        {
            const int n = tid + 512;
            float v = 0.0f;
            int i = iF1;
            if (i > 0) {
                int iw = i - cbase;
                float ph  = __fdiv_rn(cw[iw], 24000.0f);
                float sw  = __fsub_rn(ph, floorf(ph));
                float ph2 = __fdiv_rn(cw[iw - 1], 24000.0f);
                float sw2 = __fsub_rn(ph2, floorf(ph2));
                if (__fsub_rn(sw, sw2) < 0.0f)
                    v = __fmul_rn(__fdiv_rn(1.0f, __fsqrt_rn(fmaxf(fw[iw], 20.0f))), SQRT_SR);
            }
            zfr[PHI(n)] = __fmul_rn(pfNoiF1, pfWin1);
            zfi[PHI(n)] = __fmul_rn(v, pfWin1);
            float v2 = 0.0f;
            int i2 = iG1;
            if (i2 > 0) {
                int iw = i2 - cbase;
                float ph  = __fdiv_rn(cw[iw], 24000.0f);
                float sw  = __fsub_rn(ph, floorf(ph));
                float ph2 = __fdiv_rn(cw[iw - 1], 24000.0f);
                float sw2 = __fsub_rn(ph2, floorf(ph2));
                if (__fsub_rn(sw, sw2) < 0.0f)
                    v2 = __fmul_rn(__fdiv_rn(1.0f, __fsqrt_rn(fmaxf(fw[iw], 20.0f))), SQRT_SR);
            }
            zgr[PHI(n)] = __fmul_rn(pfNoiG1, pfWin1);
            zgi[PHI(n)] = __fmul_rn(v2, pfWin1);
        }
    }
    dif4(lo ? zfr : zgr, lo ? zfi : zgi, twr, twi, -1.f, u, true);
    {
        auto vbuild = [&](int p, int kk, float enF, float enG) {
            int k = rev4_10(p);
            bool cj = (k > 512);
            int p1 = rev4_10(kk);
            int p2 = rev4_10((1024 - kk) & 1023);
            float vr, vi;
            {
                float z1r = zfr[PHI(p1)], z1i = zfi[PHI(p1)];
                float z2r = zfr[PHI(p2)], z2i = -zfi[PHI(p2)];
                float Nr = 0.5f * (z1r + z2r), Ni = 0.5f * (z1i + z2i);
                float dr = z1r - z2r, di = z1i - z2i;
                float Ir = 0.5f * di, Ii = -0.5f * dr;
                float mpr = mpfr[kk], mpi2 = mpfi[kk];
                vr = Ir * mpr - Ii * mpi2 + Nr * enF;
                vi = Ir * mpi2 + Ii * mpr + Ni * enF;
                if (cj) vi = -vi;
            }
            float vgr, vgi;
            {
                float z1r = zgr[PHI(p1)], z1i = zgi[PHI(p1)];
                float z2r = zgr[PHI(p2)], z2i = -zgi[PHI(p2)];
                float Nr = 0.5f * (z1r + z2r), Ni = 0.5f * (z1i + z2i);
                float dr = z1r - z2r, di = z1i - z2i;
                float Ir = 0.5f * di, Ii = -0.5f * dr;
                float mpr = mpgr[kk], mpi2 = mpgi[kk];
                vgr = Ir * mpr - Ii * mpi2 + Nr * enG;
                vgi = Ir * mpi2 + Ii * mpr + Ni * enG;
                if (cj) vgi = -vgi;
            }
            wr_[PHI(p)] = vr - vgi;
            wi_[PHI(p)] = vi + vgr;
        };
        vbuild(tid,       kk0, (fp == 0) ? 0.0f : pfEnF0, pfEnG0);
        vbuild(tid + 512, kk1, (fp == 0) ? 0.0f : pfEnF1, pfEnG1);
    }
    dit4(wr_, wi_, twr, twi, +1.f, u, lo);      // natural: 1024*(x_f + i*x_g)
    {
        W[OFF_FR + (((size_t)(b * NFRM + fp)) << 10) + tid]       = __fmul_rn(__fmul_rn(wr_[PHI(tid)], inv), pfWin0);
        W[OFF_FR + (((size_t)(b * NFRM + fg)) << 10) + tid]       = __fmul_rn(__fmul_rn(wi_[PHI(tid)], inv), pfWin0);
        W[OFF_FR + (((size_t)(b * NFRM + fp)) << 10) + tid + 512] = __fmul_rn(__fmul_rn(wr_[PHI(tid + 512)], inv), pfWin1);
        W[OFF_FR + (((size_t)(b * NFRM + fg)) << 10) + tid + 512] = __fmul_rn(__fmul_rn(wi_[PHI(tid + 512)], inv), pfWin1);
    }
}

// swizzled f2 load from a reversed-window array: logical f2 index p,
// physical f2 index phi(p) = p ^ ((p>>4)&15)  (involution, applied on
// both the scatter-write and the read).
__device__ __forceinline__ f2 ldw(const float* A, int p) {
    int ps = p ^ ((p >> 4) & 15);
    return *(const f2*)(A + 2 * ps);
}

// K4 v5: v4's packed-fp32 triangular conv with HALF tap-chunks and DOUBLE grid.
// 1152 blocks = 8 b x 144 triangular (jt: 4(jt+1) chunks of 256 rev floats);
// 1024-out tiles, identical mapping/ring/swizzle to the passing v4, i-range
// 256->128 and T window 1536->1280. 11.3 KB LDS -> ~4.5 blocks/CU (2x waves),
// per-block main loop halved: occupancy + issue-count both improve.
__global__ __launch_bounds__(256) void k4(const float* __restrict__ rev,
                                          const float* __restrict__ win,
                                          const float* __restrict__ W,
                                          float* __restrict__ out) {
    const int tid = threadIdx.x;
    const int b = blockIdx.x / 144;
    int r = blockIdx.x - b * 144;
    int jt = 0, acc0 = 0;
    while (acc0 + 4 * (jt + 1) <= r) { acc0 += 4 * (jt + 1); ++jt; }
    const int mc = r - acc0;
    const int j0 = jt << 10, m0 = mc << 8;     // 256-float tap chunk

    __shared__ __align__(16) float TaF[1280];   // T at swizzled f2 positions
    __shared__ __align__(16) float TbF[1280];   // T shifted by 1, swizzled
    __shared__ __align__(16) float RvF[256];

    if (tid < 256)
        RvF[tid] = rev[b * KREV + m0 + tid];

    // S[x] = sigval(base + x) for x in [256,1536) (1280 values; same values as
    // v4's S[x] on that range). T[t] = S[1535 - t], t in [0,1280).
    const int base = j0 - m0 - 512;
    for (int x = 256 + tid; x < 1536; x += 256) {
        int j = base + x;
        float v = 0.f;
        if (j >= 0 && j < KREV) {
            int s = j + 512;
            int flo = (s >= 1023) ? ((s - 1023 + 255) >> 8) : 0;
            int fhi = s >> 8; if (fhi > NFRM - 1) fhi = NFRM - 1;
            float acc = 0.f, wsq = 0.f;
            for (int f = flo; f <= fhi; ++f) {
                int o = s - (f << 8);
                acc = __fadd_rn(acc, W[OFF_FR + (((size_t)(b * NFRM + f)) << 10) + o]);
                float wv = win[o];
                wsq = __fadd_rn(wsq, __fmul_rn(wv, wv));
            }
            float den = (wsq > 1e-11f) ? wsq : 1.0f;
            v = __fdiv_rn(acc, den);
        }
        int t = 1535 - x;                         // t in [0, 1279]
        {
            int pa = t >> 1, ea = t & 1;
            int ps = pa ^ ((pa >> 4) & 15);
            TaF[2 * ps + ea] = v;
        }
        int q = t - 1;                            // TbF[q] = T[q+1] = v
        if (q >= 0) {
            int pb = q >> 1, eb = q & 1;
            int ps = pb ^ ((pb >> 4) & 15);
            TbF[2 * ps + eb] = v;
        }
    }
    __syncthreads();

    const int par = tid & 1;                      // l parity
    const int g = tid >> 1;                       // 0..127
    const float* Tx = par ? TaF : TbF;            // odd l -> Ta, even l -> Tb
    const int B = 511 - 4 * g;                    // B & 3 == 3 always
    const f2* R2 = (const f2*)RvF;

    f2 a0 = (f2){0.f, 0.f}, a1 = a0, a2 = a0, a3 = a0;
    // ring slots by p&3: preload p = B-3 (slot0), B-2 (slot1), B-1 (slot2)
    f2 w0 = ldw(Tx, B - 3);
    f2 w1 = ldw(Tx, B - 2);
    f2 w2 = ldw(Tx, B - 1);
    f2 w3, rc;

    for (int i0 = 0; i0 < 128; i0 += 4) {
        // i = i0+0: new p = B+i0 (slot 3)
        w3 = ldw(Tx, B + i0);     rc = R2[i0];
        PK(a0, rc, w3); PK(a1, rc, w2); PK(a2, rc, w1); PK(a3, rc, w0);
        // i = i0+1: new p = B+i0+1 (slot 0)
        w0 = ldw(Tx, B + i0 + 1); rc = R2[i0 + 1];
        PK(a0, rc, w0); PK(a1, rc, w3); PK(a2, rc, w2); PK(a3, rc, w1);
        // i = i0+2: new p = B+i0+2 (slot 1)
        w1 = ldw(Tx, B + i0 + 2); rc = R2[i0 + 2];
        PK(a0, rc, w1); PK(a1, rc, w0); PK(a2, rc, w3); PK(a3, rc, w2);
        // i = i0+3: new p = B+i0+3 (slot 2)
        w2 = ldw(Tx, B + i0 + 3); rc = R2[i0 + 3];
        PK(a0, rc, w2); PK(a1, rc, w1); PK(a2, rc, w0); PK(a3, rc, w3);
    }

    float* o = out + (size_t)b * LTOT + OUTOFF + j0 + 8 * g + par;
    atomicAdd(o + 0, a0.x + a0.y);
    atomicAdd(o + 2, a1.x + a1.y);
    atomicAdd(o + 4, a2.x + a2.y);
    atomicAdd(o + 6, a3.x + a3.y);
}

extern "C" void kernel_launch(void* const* d_in, const int* in_sizes, int n_in,
                              void* d_out, int out_size, void* d_ws, size_t ws_size,
                              hipStream_t stream) {
    const float* f0      = (const float*)d_in[0];
    const float* env_per = (const float*)d_in[1];
    const float* env_noi = (const float*)d_in[2];
    const float* rev     = (const float*)d_in[3];
    const float* noi     = (const float*)d_in[4];
    const float* win     = (const float*)d_in[5];
    float* out = (float*)d_out;
    float* W   = (float*)d_ws;

    kfrm<<<dim3(136),  dim3(512), 0, stream>>>(f0, env_per, env_noi, noi, win, W, out);
    k4<<<dim3(1152),   dim3(256), 0, stream>>>(rev, win, W, out);
}

// Round 10
// 132.792 us; speedup vs baseline: 1.0429x; 1.0429x over previous
//
#include <hip/hip_runtime.h>
#include <math.h>

#define BB 8
#define TT 1200
#define NFFT 1024
#define BINS 513
#define LTOT 307200
#define KREV 8192
#define NFRM 34
#define NSAMP 8960
#define OUTOFF 299008          // LTOT - KREV
#define SQRT_SR 154.91933384829668f

// workspace layout (floats)
#define OFF_FR   0             // 8*34*1024 istft frames (windowed)

// LDS bank-conflict swizzle for 1024-float FFT arrays; bijective on [0,1024).
#define PHI(i) ((i) ^ ((i) >> 5))

typedef float f2 __attribute__((ext_vector_type(2)));

// packed fp32 FMA: acc.lo += b.lo*c.lo; acc.hi += b.hi*c.hi  (VOP3P, 2x fp32 rate)
#define PK(A, B, C) asm("v_pk_fma_f32 %0, %1, %2, %0" : "+v"(A) : "v"(B), "v"(C))

// base-4 digit reversal of a 10-bit index (bit-reverse, then swap adjacent bits)
__device__ __forceinline__ int rev4_10(int n) {
    int r = (int)(__brev((unsigned)n) >> 22);
    return ((r & 0x155) << 1) | ((r & 0x2AA) >> 1);
}

// radix-4 DIF, 1024 pts: input natural, output at position p = X[rev4(p)].
__device__ __forceinline__ void dif4(float* re, float* im,
                                     const float* twr, const float* twi,
                                     float dir, int u, bool act) {
#pragma unroll
    for (int s = 0; s < 5; ++s) {
        const int q = 256 >> (2 * s);
        const int sh = 8 - 2 * s;
        if (s < 2) __syncthreads();
        else       asm volatile("s_waitcnt lgkmcnt(0)" ::: "memory");
        if (act) {
            int t = u & (q - 1);
            int base = ((u >> sh) << (sh + 2)) | t;
            int i0 = PHI(base), i1 = PHI(base + q), i2 = PHI(base + 2 * q), i3 = PHI(base + 3 * q);
            float ar = re[i0], ai = im[i0];
            float br = re[i1], bi = im[i1];
            float cr = re[i2], ci = im[i2];
            float dr = re[i3], di = im[i3];
            float t0r = ar + cr, t0i = ai + ci;
            float t1r = ar - cr, t1i = ai - ci;
            float t2r = br + dr, t2i = bi + di;
            float t3r = br - dr, t3i = bi - di;
            float y0r = t0r + t2r, y0i = t0i + t2i;
            float y2r = t0r - t2r, y2i = t0i - t2i;
            float y1r = t1r - dir * t3i, y1i = t1i + dir * t3r;
            float y3r = t1r + dir * t3i, y3i = t1i - dir * t3r;
            float c1 = twr[2 * q - 1 + t], s1 = twi[2 * q - 1 + t];
            float c2 = twr[q - 1 + t],     s2 = twi[q - 1 + t];
            float w1r = c1, w1i = dir * s1;
            float w2r = c2, w2i = dir * s2;
            float w3r = c1 * c2 - s1 * s2;
            float w3i = dir * (c1 * s2 + s1 * c2);
            re[i0] = y0r;                       im[i0] = y0i;
            re[i1] = y1r * w1r - y1i * w1i;     im[i1] = y1r * w1i + y1i * w1r;
            re[i2] = y2r * w2r - y2i * w2i;     im[i2] = y2r * w2i + y2i * w2r;
            re[i3] = y3r * w3r - y3i * w3i;     im[i3] = y3r * w3i + y3i * w3r;
        }
    }
    __syncthreads();
}

// radix-4 DIT, 1024 pts: input at position p = x[rev4(p)], output natural.
__device__ __forceinline__ void dit4(float* re, float* im,
                                     const float* twr, const float* twi,
                                     float dir, int u, bool act) {
#pragma unroll
    for (int s = 0; s < 5; ++s) {
        const int q = 1 << (2 * s);
        const int sh = 2 * s;
        if (s == 0 || s == 4) __syncthreads();
        else                  asm volatile("s_waitcnt lgkmcnt(0)" ::: "memory");
        if (act) {
            int t = u & (q - 1);
            int base = ((u >> sh) << (sh + 2)) | t;
            int i0 = PHI(base), i1 = PHI(base + q), i2 = PHI(base + 2 * q), i3 = PHI(base + 3 * q);
            float c1 = twr[2 * q - 1 + t], s1 = twi[2 * q - 1 + t];
            float c2 = twr[q - 1 + t],     s2 = twi[q - 1 + t];
            float w1r = c1, w1i = dir * s1;
            float w2r = c2, w2i = dir * s2;
            float w3r = c1 * c2 - s1 * s2;
            float w3i = dir * (c1 * s2 + s1 * c2);
            float ar = re[i0], ai = im[i0];
            float xr = re[i1], xi = im[i1];
            float yr = re[i2], yi = im[i2];
            float zr = re[i3], zi = im[i3];
            float br = xr * w1r - xi * w1i, bi = xr * w1i + xi * w1r;
            float cr = yr * w2r - yi * w2i, ci = yr * w2i + yi * w2r;
            float dr = zr * w3r - zi * w3i, di = zr * w3i + zi * w3r;
            float t0r = ar + cr, t0i = ai + ci;
            float t1r = ar - cr, t1i = ai - ci;
            float t2r = br + dr, t2i = bi + di;
            float t3r = br - dr, t3i = bi - di;
            re[i0] = t0r + t2r;            im[i0] = t0i + t2i;
            re[i2] = t0r - t2r;            im[i2] = t0i - t2i;
            re[i1] = t1r - dir * t3i;      im[i1] = t1i + dir * t3r;
            re[i3] = t1r + dir * t3i;      im[i3] = t1i - dir * t3r;
        }
    }
    __syncthreads();
}

// tree-scan level offsets within L
#define LV1 0
#define LV2 4480
#define LV3 6720
#define LV4 7840
#define LV5 8400
#define LV6 8680
#define LV7 8820
#define LV8 8890
#define LV9 8925
#define LV10 8942
#define LV11 8950
#define LV12 8954
#define LV13 8956

// KFRM: round-1 configuration verbatim (pinned at ~42.8 us across 6 structural
// variants; untouched).
__global__ __launch_bounds__(512) void kfrm(const float* __restrict__ f0,
                                            const float* __restrict__ env_per,
                                            const float* __restrict__ env_noi,
                                            const float* __restrict__ noi,
                                            const float* __restrict__ win,
                                            float* __restrict__ W,
                                            float* __restrict__ out) {
    const int bid = blockIdx.x;           // 0..135
    const int tid = threadIdx.x;
    const int b = bid / 17;
    const int fp = (bid - b * 17) * 2;    // f = fp, g = fp+1
    const int fg = fp + 1;

    __shared__ __align__(16) float SMEM[17917];   // union: {F[8960],L[8957]} | FFT arrays
    __shared__ float cw[1281], fw[1281];
    __shared__ float twr[1023], twi[1023];

    // ---- early prefetch of every scattered global read
    const int idxF = (fp > 0) ? (fp - 1) : 0;
    const int idxG = fg - 1;
    float pfEpF = 0.f, pfEpG = 0.f, pfEpF2 = 0.f, pfEpG2 = 0.f;
    {
        pfEpF = env_per[((size_t)(b * BINS + tid)) * TT + idxF];
        pfEpG = env_per[((size_t)(b * BINS + tid)) * TT + idxG];
        if (tid == 0) {
            pfEpF2 = env_per[((size_t)(b * BINS + 512)) * TT + idxF];
            pfEpG2 = env_per[((size_t)(b * BINS + 512)) * TT + idxG];
        }
    }
    const float pfF0F = f0[b * TT + idxF];
    const float pfF0G = f0[b * TT + idxG];
    int ktmp0 = rev4_10(tid);
    const int kk0 = (ktmp0 <= 512) ? ktmp0 : 1024 - ktmp0;
    int ktmp1 = rev4_10(tid + 512);
    const int kk1 = (ktmp1 <= 512) ? ktmp1 : 1024 - ktmp1;
    const float pfEnF0 = env_noi[((size_t)(b * BINS + kk0)) * TT + idxF];
    const float pfEnG0 = env_noi[((size_t)(b * BINS + kk0)) * TT + idxG];
    const float pfEnF1 = env_noi[((size_t)(b * BINS + kk1)) * TT + idxF];
    const float pfEnG1 = env_noi[((size_t)(b * BINS + kk1)) * TT + idxG];
    int iF0 = 256 * fp + tid - 512; if (iF0 < 0) iF0 = -iF0;
    const int iF1 = 256 * fp + tid;
    int iG0 = 256 * fg + tid - 512; if (iG0 < 0) iG0 = -iG0;
    const int iG1 = 256 * fg + tid;
    const float pfNoiF0 = noi[(size_t)b * LTOT + iF0];
    const float pfNoiF1 = noi[(size_t)b * LTOT + iF1];
    const float pfNoiG0 = noi[(size_t)b * LTOT + iG0];
    const float pfNoiG1 = noi[(size_t)b * LTOT + iG1];
    const float pfWin0 = win[tid];
    const float pfWin1 = win[tid + 512];

    // ---- phase 0: zero-fill out (grid-stride), twiddles
    {
        float4* out4 = (float4*)out;
        int g = bid * 512 + tid;
        for (int idx = g; idx < (BB * LTOT) / 4; idx += 136 * 512)
            out4[idx] = make_float4(0.f, 0.f, 0.f, 0.f);
    }
    for (int x = tid; x < 1023; x += 512) {
        int hb = 31 - __clz(x + 1);
        int half = 1 << hb;
        int t = (x + 1) - half;
        float a = 3.14159265358979323846f * ((float)t / (float)half);
        float sv, cv; sincosf(a, &sv, &cv);
        twr[x] = cv; twi[x] = sv;
    }

    // ---- phase 1: bit-exact f0 upsample + tree cumsum (merged levels)
    float* F = SMEM;            // 8960
    float* L = SMEM + 8960;     // 8957
    for (int i = tid; i < NSAMP; i += 512) {
        float src = __fsub_rn(__fdiv_rn(__fadd_rn((float)i, 0.5f), 256.0f), 0.5f);
        src = fminf(fmaxf(src, 0.0f), (float)(TT - 1));
        int i0 = (int)floorf(src);
        int i1 = i0 + 1; if (i1 > TT - 1) i1 = TT - 1;
        float w = __fsub_rn(src, (float)i0);
        float a0 = __fmul_rn(f0[b * TT + i0], __fsub_rn(1.0f, w));
        float a1 = __fmul_rn(f0[b * TT + i1], w);
        F[i] = __fadd_rn(a0, a1);
    }
    __syncthreads();
    for (int j = tid; j < 2240; j += 512) {           // levels 1+2
        float a = __fadd_rn(F[4*j],     F[4*j + 1]);
        float c = __fadd_rn(F[4*j + 2], F[4*j + 3]);
        L[LV1 + 2*j] = a; L[LV1 + 2*j + 1] = c;
        L[LV2 + j] = __fadd_rn(a, c);
    }
    __syncthreads();
    for (int j = tid; j < 560; j += 512) {            // levels 3+4
        float a = __fadd_rn(L[LV2 + 4*j],     L[LV2 + 4*j + 1]);
        float c = __fadd_rn(L[LV2 + 4*j + 2], L[LV2 + 4*j + 3]);
        L[LV3 + 2*j] = a; L[LV3 + 2*j + 1] = c;
        L[LV4 + j] = __fadd_rn(a, c);
    }
    __syncthreads();
    if (tid < 140) {                                  // levels 5+6
        int j = tid;
        float a = __fadd_rn(L[LV4 + 4*j],     L[LV4 + 4*j + 1]);
        float c = __fadd_rn(L[LV4 + 4*j + 2], L[LV4 + 4*j + 3]);
        L[LV5 + 2*j] = a; L[LV5 + 2*j + 1] = c;
        L[LV6 + j] = __fadd_rn(a, c);
    }
    __syncthreads();
    if (tid < 35) {                                   // levels 7+8
        int j = tid;
        float a = __fadd_rn(L[LV6 + 4*j],     L[LV6 + 4*j + 1]);
        float c = __fadd_rn(L[LV6 + 4*j + 2], L[LV6 + 4*j + 3]);
        L[LV7 + 2*j] = a; L[LV7 + 2*j + 1] = c;
        L[LV8 + j] = __fadd_rn(a, c);
    }
    __syncthreads();
    if (tid < 9) {                                    // levels 9+10 (L9 has 17 nodes)
        int j = tid;
        if (j < 8) {
            float a = __fadd_rn(L[LV8 + 4*j],     L[LV8 + 4*j + 1]);
            float c = __fadd_rn(L[LV8 + 4*j + 2], L[LV8 + 4*j + 3]);
            L[LV9 + 2*j] = a; L[LV9 + 2*j + 1] = c;
            L[LV10 + j] = __fadd_rn(a, c);
        } else {
            L[LV9 + 16] = __fadd_rn(L[LV8 + 32], L[LV8 + 33]);
        }
    }
    __syncthreads();
    if (tid == 0) {                                   // levels 11..13
        float a0 = __fadd_rn(L[LV10 + 0], L[LV10 + 1]);
        float a1 = __fadd_rn(L[LV10 + 2], L[LV10 + 3]);
        float a2 = __fadd_rn(L[LV10 + 4], L[LV10 + 5]);
        float a3 = __fadd_rn(L[LV10 + 6], L[LV10 + 7]);
        L[LV11 + 0] = a0; L[LV11 + 1] = a1; L[LV11 + 2] = a2; L[LV11 + 3] = a3;
        float b0 = __fadd_rn(a0, a1), b1 = __fadd_rn(a2, a3);
        L[LV12 + 0] = b0; L[LV12 + 1] = b1;
        L[LV13 + 0] = __fadd_rn(b0, b1);
    }
    __syncthreads();
    const int cbase = (fp >= 3) ? (256 * fp - 513) : 0;
    {
        const int offs[14] = {0, LV1, LV2, LV3, LV4, LV5, LV6, LV7, LV8, LV9, LV10, LV11, LV12, LV13};
        for (int w = tid; w < 1281; w += 512) {
            int p = cbase + w;
            if (p < NSAMP) {
                int n = p + 1;
                float acc = 0.f; int pos = 0; bool first = true;
#pragma unroll
                for (int k = 13; k >= 1; --k) {
                    if ((n >> k) & 1) {
                        float t = L[offs[k] + (pos >> k)];
                        acc = first ? t : __fadd_rn(acc, t);
                        first = false;
                        pos += (1 << k);
                    }
                }
                if (n & 1) {
                    float t = F[pos];
                    acc = first ? t : __fadd_rn(acc, t);
                }
                cw[w] = acc;
                fw[w] = F[p];
            }
        }
    }
    __syncthreads();

    // ---- phase 2: FFT pipeline (union reused)
    float* wr_  = SMEM;          // 1024
    float* wi_  = SMEM + 1024;
    float* zfr  = SMEM + 2048;
    float* zfi  = SMEM + 3072;
    float* zgr  = SMEM + 4096;
    float* zgi  = SMEM + 5120;
    float* mpfr = SMEM + 6144;   // 513 each
    float* mpfi = SMEM + 6660;
    float* mpgr = SMEM + 7176;
    float* mpgi = SMEM + 7692;
    const int u = tid & 255;
    const bool lo = (tid < 256);

    {
        const bool gF = (fp > 0) && (pfF0F > 20.0f);
        const bool gG = (pfF0G > 20.0f);
        mpfr[tid] = logf(fmaxf(gF ? pfEpF : 0.0f, 1e-5f));
        mpgr[tid] = logf(fmaxf(gG ? pfEpG : 0.0f, 1e-5f));
        if (tid == 0) {
            mpfr[512] = logf(fmaxf(gF ? pfEpF2 : 0.0f, 1e-5f));
            mpgr[512] = logf(fmaxf(gG ? pfEpG2 : 0.0f, 1e-5f));
        }
    }
    __syncthreads();
#pragma unroll
    for (int r = 0; r < 2; ++r) {
        int n = tid + 512 * r;
        int kv = (n <= 512) ? n : 1024 - n;
        wr_[PHI(n)] = mpfr[kv];
        wi_[PHI(n)] = mpgr[kv];
    }
    dif4(wr_, wi_, twr, twi, -1.f, u, lo);
    const float inv = 1.0f / 1024.0f;
#pragma unroll
    for (int r = 0; r < 2; ++r) {
        int p = tid + 512 * r;
        int n = rev4_10(p);
        float wgt = (n == 0 || n == 512) ? inv : ((n < 512) ? 2.0f * inv : 0.0f);
        wr_[PHI(p)] *= wgt;
        wi_[PHI(p)] *= wgt;
    }
    dit4(wr_, wi_, twr, twi, -1.f, u, lo);      // Y natural
    for (int k = tid; k < BINS; k += 512) {
        int mk = (1024 - k) & 1023;
        float yr = wr_[PHI(k)], yi = wi_[PHI(k)];
        float ymr = wr_[PHI(mk)], ymi = -wi_[PHI(mk)];
        float Lfr = 0.5f * (yr + ymr), Lfi = 0.5f * (yi + ymi);
        float dr = yr - ymr, di = yi - ymi;
        float Lgr = 0.5f * di, Lgi = -0.5f * dr;
        float ef = expf(Lfr);
        mpfr[k] = ef * cosf(Lfi); mpfi[k] = ef * sinf(Lfi);
        float eg = expf(Lgr);
        mpgr[k] = eg * cosf(Lgi); mpgi[k] = eg * sinf(Lgi);
    }
    __syncthreads();
    {
        {
            const int n = tid;
            float v = 0.0f;
            int i = iF0;
            if (i > 0) {
                int iw = i - cbase;
                float ph  = __fdiv_rn(cw[iw], 24000.0f);
                float sw  = __fsub_rn(ph, floorf(ph));
                float ph2 = __fdiv_rn(cw[iw - 1], 24000.0f);
                float sw2 = __fsub_rn(ph2, floorf(ph2));
                if (__fsub_rn(sw, sw2) < 0.0f)
                    v = __fmul_rn(__fdiv_rn(1.0f, __fsqrt_rn(fmaxf(fw[iw], 20.0f))), SQRT_SR);
            }
            zfr[PHI(n)] = __fmul_rn(pfNoiF0, pfWin0);
            zfi[PHI(n)] = __fmul_rn(v, pfWin0);
            float v2 = 0.0f;
            int i2 = iG0;
            if (i2 > 0) {
                int iw = i2 - cbase;
                float ph  = __fdiv_rn(cw[iw], 24000.0f);
                float sw  = __fsub_rn(ph, floorf(ph));
                float ph2 = __fdiv_rn(cw[iw - 1], 24000.0f);
                float sw2 = __fsub_rn(ph2, floorf(ph2));
                if (__fsub_rn(sw, sw2) < 0.0f)
                    v2 = __fmul_rn(__fdiv_rn(1.0f, __fsqrt_rn(fmaxf(fw[iw], 20.0f))), SQRT_SR);
            }
            zgr[PHI(n)] = __fmul_rn(pfNoiG0, pfWin0);
            zgi[PHI(n)] = __fmul_rn(v2, pfWin0);
        }
        {
            const int n = tid + 512;
            float v = 0.0f;
            int i = iF1;
            if (i > 0) {
                int iw = i - cbase;
                float ph  = __fdiv_rn(cw[iw], 24000.0f);
                float sw  = __fsub_rn(ph, floorf(ph));
                float ph2 = __fdiv_rn(cw[iw - 1], 24000.0f);
                float sw2 = __fsub_rn(ph2, floorf(ph2));
                if (__fsub_rn(sw, sw2) < 0.0f)
                    v = __fmul_rn(__fdiv_rn(1.0f, __fsqrt_rn(fmaxf(fw[iw], 20.0f))), SQRT_SR);
            }
            zfr[PHI(n)] = __fmul_rn(pfNoiF1, pfWin1);
            zfi[PHI(n)] = __fmul_rn(v, pfWin1);
            float v2 = 0.0f;
            int i2 = iG1;
            if (i2 > 0) {
                int iw = i2 - cbase;
                float ph  = __fdiv_rn(cw[iw], 24000.0f);
                float sw  = __fsub_rn(ph, floorf(ph));
                float ph2 = __fdiv_rn(cw[iw - 1], 24000.0f);
                float sw2 = __fsub_rn(ph2, floorf(ph2));
                if (__fsub_rn(sw, sw2) < 0.0f)
                    v2 = __fmul_rn(__fdiv_rn(1.0f, __fsqrt_rn(fmaxf(fw[iw], 20.0f))), SQRT_SR);
            }
            zgr[PHI(n)] = __fmul_rn(pfNoiG1, pfWin1);
            zgi[PHI(n)] = __fmul_rn(v2, pfWin1);
        }
    }
    dif4(lo ? zfr : zgr, lo ? zfi : zgi, twr, twi, -1.f, u, true);
    {
        auto vbuild = [&](int p, int kk, float enF, float enG) {
            int k = rev4_10(p);
            bool cj = (k > 512);
            int p1 = rev4_10(kk);
            int p2 = rev4_10((1024 - kk) & 1023);
            float vr, vi;
            {
                float z1r = zfr[PHI(p1)], z1i = zfi[PHI(p1)];
                float z2r = zfr[PHI(p2)], z2i = -zfi[PHI(p2)];
                float Nr = 0.5f * (z1r + z2r), Ni = 0.5f * (z1i + z2i);
                float dr = z1r - z2r, di = z1i - z2i;
                float Ir = 0.5f * di, Ii = -0.5f * dr;
                float mpr = mpfr[kk], mpi2 = mpfi[kk];
                vr = Ir * mpr - Ii * mpi2 + Nr * enF;
                vi = Ir * mpi2 + Ii * mpr + Ni * enF;
                if (cj) vi = -vi;
            }
            float vgr, vgi;
            {
                float z1r = zgr[PHI(p1)], z1i = zgi[PHI(p1)];
                float z2r = zgr[PHI(p2)], z2i = -zgi[PHI(p2)];
                float Nr = 0.5f * (z1r + z2r), Ni = 0.5f * (z1i + z2i);
                float dr = z1r - z2r, di = z1i - z2i;
                float Ir = 0.5f * di, Ii = -0.5f * dr;
                float mpr = mpgr[kk], mpi2 = mpgi[kk];
                vgr = Ir * mpr - Ii * mpi2 + Nr * enG;
                vgi = Ir * mpi2 + Ii * mpr + Ni * enG;
                if (cj) vgi = -vgi;
            }
            wr_[PHI(p)] = vr - vgi;
            wi_[PHI(p)] = vi + vgr;
        };
        vbuild(tid,       kk0, (fp == 0) ? 0.0f : pfEnF0, pfEnG0);
        vbuild(tid + 512, kk1, (fp == 0) ? 0.0f : pfEnF1, pfEnG1);
    }
    dit4(wr_, wi_, twr, twi, +1.f, u, lo);      // natural: 1024*(x_f + i*x_g)
    {
        W[OFF_FR + (((size_t)(b * NFRM + fp)) << 10) + tid]       = __fmul_rn(__fmul_rn(wr_[PHI(tid)], inv), pfWin0);
        W[OFF_FR + (((size_t)(b * NFRM + fg)) << 10) + tid]       = __fmul_rn(__fmul_rn(wi_[PHI(tid)], inv), pfWin0);
        W[OFF_FR + (((size_t)(b * NFRM + fp)) << 10) + tid + 512] = __fmul_rn(__fmul_rn(wr_[PHI(tid + 512)], inv), pfWin1);
        W[OFF_FR + (((size_t)(b * NFRM + fg)) << 10) + tid + 512] = __fmul_rn(__fmul_rn(wi_[PHI(tid + 512)], inv), pfWin1);
    }
}

// swizzled f2 load from a reversed-window array: logical f2 index p,
// physical f2 index phi(p) = p ^ ((p>>4)&15)  (involution, applied on
// both the scatter-write and the read).
__device__ __forceinline__ f2 ldw(const float* A, int p) {
    int ps = p ^ ((p >> 4) & 15);
    return *(const f2*)(A + 2 * ps);
}

// K4 v6: v4 (proven 134.48 total) + WSQ table for the S-build.
// For every in-range sample with s >= 1023 the OLA covers exactly 4 frames
// with offsets {s&255, +256, +512, +768}, so wsq depends only on s&255.
// WSQ[] is built once per block with the reference's exact __fadd_rn chain
// order (frames ascending -> offsets descending) => bit-identical values,
// same __fdiv_rn => bit-identical output. The per-element 4-frame path
// drops 4 win loads + 4 mul + 4 add and unrolls the acc chain.
__global__ __launch_bounds__(256) void k4(const float* __restrict__ rev,
                                          const float* __restrict__ win,
                                          const float* __restrict__ W,
                                          float* __restrict__ out) {
    const int tid = threadIdx.x;
    const int b = blockIdx.x / 72;
    int r = blockIdx.x - b * 72;
    int jt = 0, acc0 = 0;
    while (acc0 + 2 * (jt + 1) <= r) { acc0 += 2 * (jt + 1); ++jt; }
    const int mc = r - acc0;
    const int j0 = jt << 10, m0 = mc << 9;

    __shared__ __align__(16) float TaF[1536];   // T at swizzled f2 positions
    __shared__ __align__(16) float TbF[1536];   // T shifted by 1, swizzled
    __shared__ __align__(16) float RvF[512];
    __shared__ float WSQ[256];

    for (int x = tid; x < 512; x += 256)
        RvF[x] = rev[b * KREV + m0 + x];

    // WSQ[t] = w2(t+768) + w2(t+512) + w2(t+256) + w2(t), in the reference's
    // add order (frames ascending = offsets descending), starting from 0.
    {
        int t = tid;
        float w3v = win[t + 768], w2v = win[t + 512], w1v = win[t + 256], w0v = win[t];
        float wsq = __fadd_rn(0.0f, __fmul_rn(w3v, w3v));
        wsq = __fadd_rn(wsq, __fmul_rn(w2v, w2v));
        wsq = __fadd_rn(wsq, __fmul_rn(w1v, w1v));
        wsq = __fadd_rn(wsq, __fmul_rn(w0v, w0v));
        WSQ[t] = wsq;
    }
    __syncthreads();

    const int base = j0 - m0 - 512;
    for (int x = tid; x < 1536; x += 256) {
        int j = base + x;
        float v = 0.f;
        if (j >= 0 && j < KREV) {
            int s = j + 512;
            if (s >= 1023) {
                // 4-frame fast path: flo = (s-768)>>8, fhi = s>>8 (no clamp:
                // s <= 8703 -> fhi <= 33 = NFRM-1). wsq = WSQ[s&255] > 1e-11.
                int flo = (s - 768) >> 8;
                const float* Wb = W + OFF_FR + (((size_t)(b * NFRM + flo)) << 10);
                int o0 = s - (flo << 8);           // (s&255) + 768
                float acc = __fadd_rn(0.0f, Wb[o0]);
                acc = __fadd_rn(acc, Wb[1024 + o0 - 256]);
                acc = __fadd_rn(acc, Wb[2048 + o0 - 512]);
                acc = __fadd_rn(acc, Wb[3072 + o0 - 768]);
                v = __fdiv_rn(acc, WSQ[s & 255]);
            } else {
                int flo = 0;
                int fhi = s >> 8;
                float acc = 0.f, wsq = 0.f;
                for (int f = flo; f <= fhi; ++f) {
                    int o = s - (f << 8);
                    acc = __fadd_rn(acc, W[OFF_FR + (((size_t)(b * NFRM + f)) << 10) + o]);
                    float wv = win[o];
                    wsq = __fadd_rn(wsq, __fmul_rn(wv, wv));
                }
                float den = (wsq > 1e-11f) ? wsq : 1.0f;
                v = __fdiv_rn(acc, den);
            }
        }
        int t = 1535 - x;                         // T[t] = v
        {
            int pa = t >> 1, ea = t & 1;
            int ps = pa ^ ((pa >> 4) & 15);
            TaF[2 * ps + ea] = v;
        }
        int q = t - 1;                            // TbF[q] = T[q+1] = v
        if (q >= 0) {
            int pb = q >> 1, eb = q & 1;
            int ps = pb ^ ((pb >> 4) & 15);
            TbF[2 * ps + eb] = v;
        }
    }
    __syncthreads();

    const int par = tid & 1;                      // l parity
    const int g = tid >> 1;                       // 0..127
    const float* Tx = par ? TaF : TbF;            // odd l -> Ta, even l -> Tb
    const int B = 511 - 4 * g;                    // B & 3 == 3 always
    const f2* R2 = (const f2*)RvF;

    f2 a0 = (f2){0.f, 0.f}, a1 = a0, a2 = a0, a3 = a0;
    // ring slots by p&3: preload p = B-3 (slot0), B-2 (slot1), B-1 (slot2)
    f2 w0 = ldw(Tx, B - 3);
    f2 w1 = ldw(Tx, B - 2);
    f2 w2 = ldw(Tx, B - 1);
    f2 w3, rc;

    for (int i0 = 0; i0 < 256; i0 += 4) {
        // i = i0+0: new p = B+i0 (slot 3)
        w3 = ldw(Tx, B + i0);     rc = R2[i0];
        PK(a0, rc, w3); PK(a1, rc, w2); PK(a2, rc, w1); PK(a3, rc, w0);
        // i = i0+1: new p = B+i0+1 (slot 0)
        w0 = ldw(Tx, B + i0 + 1); rc = R2[i0 + 1];
        PK(a0, rc, w0); PK(a1, rc, w3); PK(a2, rc, w2); PK(a3, rc, w1);
        // i = i0+2: new p = B+i0+2 (slot 1)
        w1 = ldw(Tx, B + i0 + 2); rc = R2[i0 + 2];
        PK(a0, rc, w1); PK(a1, rc, w0); PK(a2, rc, w3); PK(a3, rc, w2);
        // i = i0+3: new p = B+i0+3 (slot 2)
        w2 = ldw(Tx, B + i0 + 3); rc = R2[i0 + 3];
        PK(a0, rc, w2); PK(a1, rc, w1); PK(a2, rc, w0); PK(a3, rc, w3);
    }

    float* o = out + (size_t)b * LTOT + OUTOFF + j0 + 8 * g + par;
    atomicAdd(o + 0, a0.x + a0.y);
    atomicAdd(o + 2, a1.x + a1.y);
    atomicAdd(o + 4, a2.x + a2.y);
    atomicAdd(o + 6, a3.x + a3.y);
}

extern "C" void kernel_launch(void* const* d_in, const int* in_sizes, int n_in,
                              void* d_out, int out_size, void* d_ws, size_t ws_size,
                              hipStream_t stream) {
    const float* f0      = (const float*)d_in[0];
    const float* env_per = (const float*)d_in[1];
    const float* env_noi = (const float*)d_in[2];
    const float* rev     = (const float*)d_in[3];
    const float* noi     = (const float*)d_in[4];
    const float* win     = (const float*)d_in[5];
    float* out = (float*)d_out;
    float* W   = (float*)d_ws;

    kfrm<<<dim3(136), dim3(512), 0, stream>>>(f0, env_per, env_noi, noi, win, W, out);
    k4<<<dim3(576),   dim3(256), 0, stream>>>(rev, win, W, out);
}

// Round 12
// 132.325 us; speedup vs baseline: 1.0466x; 1.0035x over previous
//
#include <hip/hip_runtime.h>
#include <math.h>

#define BB 8
#define TT 1200
#define NFFT 1024
#define BINS 513
#define LTOT 307200
#define KREV 8192
#define NFRM 34
#define NSAMP 8960
#define OUTOFF 299008          // LTOT - KREV
#define SQRT_SR 154.91933384829668f

// workspace layout (floats)
#define OFF_FR   0             // 8*34*1024 istft frames (windowed)

// LDS bank-conflict swizzle for 1024-float FFT arrays; bijective on [0,1024).
#define PHI(i) ((i) ^ ((i) >> 5))

typedef float f2 __attribute__((ext_vector_type(2)));
typedef float f4 __attribute__((ext_vector_type(4)));   // clang ext-vector: valid for nontemporal builtins

// packed fp32 FMA: acc.lo += b.lo*c.lo; acc.hi += b.hi*c.hi  (VOP3P, 2x fp32 rate)
#define PK(A, B, C) asm("v_pk_fma_f32 %0, %1, %2, %0" : "+v"(A) : "v"(B), "v"(C))

// base-4 digit reversal of a 10-bit index (bit-reverse, then swap adjacent bits)
__device__ __forceinline__ int rev4_10(int n) {
    int r = (int)(__brev((unsigned)n) >> 22);
    return ((r & 0x155) << 1) | ((r & 0x2AA) >> 1);
}

// radix-4 DIF, 1024 pts: input natural, output at position p = X[rev4(p)].
__device__ __forceinline__ void dif4(float* re, float* im,
                                     const float* twr, const float* twi,
                                     float dir, int u, bool act) {
#pragma unroll
    for (int s = 0; s < 5; ++s) {
        const int q = 256 >> (2 * s);
        const int sh = 8 - 2 * s;
        if (s < 2) __syncthreads();
        else       asm volatile("s_waitcnt lgkmcnt(0)" ::: "memory");
        if (act) {
            int t = u & (q - 1);
            int base = ((u >> sh) << (sh + 2)) | t;
            int i0 = PHI(base), i1 = PHI(base + q), i2 = PHI(base + 2 * q), i3 = PHI(base + 3 * q);
            float ar = re[i0], ai = im[i0];
            float br = re[i1], bi = im[i1];
            float cr = re[i2], ci = im[i2];
            float dr = re[i3], di = im[i3];
            float t0r = ar + cr, t0i = ai + ci;
            float t1r = ar - cr, t1i = ai - ci;
            float t2r = br + dr, t2i = bi + di;
            float t3r = br - dr, t3i = bi - di;
            float y0r = t0r + t2r, y0i = t0i + t2i;
            float y2r = t0r - t2r, y2i = t0i - t2i;
            float y1r = t1r - dir * t3i, y1i = t1i + dir * t3r;
            float y3r = t1r + dir * t3i, y3i = t1i - dir * t3r;
            float c1 = twr[2 * q - 1 + t], s1 = twi[2 * q - 1 + t];
            float c2 = twr[q - 1 + t],     s2 = twi[q - 1 + t];
            float w1r = c1, w1i = dir * s1;
            float w2r = c2, w2i = dir * s2;
            float w3r = c1 * c2 - s1 * s2;
            float w3i = dir * (c1 * s2 + s1 * c2);
            re[i0] = y0r;                       im[i0] = y0i;
            re[i1] = y1r * w1r - y1i * w1i;     im[i1] = y1r * w1i + y1i * w1r;
            re[i2] = y2r * w2r - y2i * w2i;     im[i2] = y2r * w2i + y2i * w2r;
            re[i3] = y3r * w3r - y3i * w3i;     im[i3] = y3r * w3i + y3i * w3r;
        }
    }
    __syncthreads();
}

// radix-4 DIT, 1024 pts: input at position p = x[rev4(p)], output natural.
__device__ __forceinline__ void dit4(float* re, float* im,
                                     const float* twr, const float* twi,
                                     float dir, int u, bool act) {
#pragma unroll
    for (int s = 0; s < 5; ++s) {
        const int q = 1 << (2 * s);
        const int sh = 2 * s;
        if (s == 0 || s == 4) __syncthreads();
        else                  asm volatile("s_waitcnt lgkmcnt(0)" ::: "memory");
        if (act) {
            int t = u & (q - 1);
            int base = ((u >> sh) << (sh + 2)) | t;
            int i0 = PHI(base), i1 = PHI(base + q), i2 = PHI(base + 2 * q), i3 = PHI(base + 3 * q);
            float c1 = twr[2 * q - 1 + t], s1 = twi[2 * q - 1 + t];
            float c2 = twr[q - 1 + t],     s2 = twi[q - 1 + t];
            float w1r = c1, w1i = dir * s1;
            float w2r = c2, w2i = dir * s2;
            float w3r = c1 * c2 - s1 * s2;
            float w3i = dir * (c1 * s2 + s1 * c2);
            float ar = re[i0], ai = im[i0];
            float xr = re[i1], xi = im[i1];
            float yr = re[i2], yi = im[i2];
            float zr = re[i3], zi = im[i3];
            float br = xr * w1r - xi * w1i, bi = xr * w1i + xi * w1r;
            float cr = yr * w2r - yi * w2i, ci = yr * w2i + yi * w2r;
            float dr = zr * w3r - zi * w3i, di = zr * w3i + zi * w3r;
            float t0r = ar + cr, t0i = ai + ci;
            float t1r = ar - cr, t1i = ai - ci;
            float t2r = br + dr, t2i = bi + di;
            float t3r = br - dr, t3i = bi - di;
            re[i0] = t0r + t2r;            im[i0] = t0i + t2i;
            re[i2] = t0r - t2r;            im[i2] = t0i - t2i;
            re[i1] = t1r - dir * t3i;      im[i1] = t1i + dir * t3r;
            re[i3] = t1r + dir * t3i;      im[i3] = t1i - dir * t3r;
        }
    }
    __syncthreads();
}

// tree-scan level offsets within L
#define LV1 0
#define LV2 4480
#define LV3 6720
#define LV4 7840
#define LV5 8400
#define LV6 8680
#define LV7 8820
#define LV8 8890
#define LV9 8925
#define LV10 8942
#define LV11 8950
#define LV12 8954
#define LV13 8956

// KFRM: round-1 configuration; zero-fill uses NON-TEMPORAL (nt) stores via a
// clang ext_vector f4 (HIP float4 is rejected by the builtin). Theory: normal
// stores RFO-read the 9.8 MB fill region (kfrm FETCH_SIZE 10.9 MB vs ~1.1 MB
// of actual inputs) — the fill, not the interior, is kfrm's pinned ~38 us.
__global__ __launch_bounds__(512) void kfrm(const float* __restrict__ f0,
                                            const float* __restrict__ env_per,
                                            const float* __restrict__ env_noi,
                                            const float* __restrict__ noi,
                                            const float* __restrict__ win,
                                            float* __restrict__ W,
                                            float* __restrict__ out) {
    const int bid = blockIdx.x;           // 0..135
    const int tid = threadIdx.x;
    const int b = bid / 17;
    const int fp = (bid - b * 17) * 2;    // f = fp, g = fp+1
    const int fg = fp + 1;

    __shared__ __align__(16) float SMEM[17917];   // union: {F[8960],L[8957]} | FFT arrays
    __shared__ float cw[1281], fw[1281];
    __shared__ float twr[1023], twi[1023];

    // ---- early prefetch of every scattered global read
    const int idxF = (fp > 0) ? (fp - 1) : 0;
    const int idxG = fg - 1;
    float pfEpF = 0.f, pfEpG = 0.f, pfEpF2 = 0.f, pfEpG2 = 0.f;
    {
        pfEpF = env_per[((size_t)(b * BINS + tid)) * TT + idxF];
        pfEpG = env_per[((size_t)(b * BINS + tid)) * TT + idxG];
        if (tid == 0) {
            pfEpF2 = env_per[((size_t)(b * BINS + 512)) * TT + idxF];
            pfEpG2 = env_per[((size_t)(b * BINS + 512)) * TT + idxG];
        }
    }
    const float pfF0F = f0[b * TT + idxF];
    const float pfF0G = f0[b * TT + idxG];
    int ktmp0 = rev4_10(tid);
    const int kk0 = (ktmp0 <= 512) ? ktmp0 : 1024 - ktmp0;
    int ktmp1 = rev4_10(tid + 512);
    const int kk1 = (ktmp1 <= 512) ? ktmp1 : 1024 - ktmp1;
    const float pfEnF0 = env_noi[((size_t)(b * BINS + kk0)) * TT + idxF];
    const float pfEnG0 = env_noi[((size_t)(b * BINS + kk0)) * TT + idxG];
    const float pfEnF1 = env_noi[((size_t)(b * BINS + kk1)) * TT + idxF];
    const float pfEnG1 = env_noi[((size_t)(b * BINS + kk1)) * TT + idxG];
    int iF0 = 256 * fp + tid - 512; if (iF0 < 0) iF0 = -iF0;
    const int iF1 = 256 * fp + tid;
    int iG0 = 256 * fg + tid - 512; if (iG0 < 0) iG0 = -iG0;
    const int iG1 = 256 * fg + tid;
    const float pfNoiF0 = noi[(size_t)b * LTOT + iF0];
    const float pfNoiF1 = noi[(size_t)b * LTOT + iF1];
    const float pfNoiG0 = noi[(size_t)b * LTOT + iG0];
    const float pfNoiG1 = noi[(size_t)b * LTOT + iG1];
    const float pfWin0 = win[tid];
    const float pfWin1 = win[tid + 512];

    // ---- phase 0: zero-fill out (grid-stride, NON-TEMPORAL), twiddles
    {
        f4* out4 = (f4*)out;
        const f4 z = (f4){0.f, 0.f, 0.f, 0.f};
        int g = bid * 512 + tid;
        for (int idx = g; idx < (BB * LTOT) / 4; idx += 136 * 512)
            __builtin_nontemporal_store(z, &out4[idx]);
    }
    for (int x = tid; x < 1023; x += 512) {
        int hb = 31 - __clz(x + 1);
        int half = 1 << hb;
        int t = (x + 1) - half;
        float a = 3.14159265358979323846f * ((float)t / (float)half);
        float sv, cv; sincosf(a, &sv, &cv);
        twr[x] = cv; twi[x] = sv;
    }

    // ---- phase 1: bit-exact f0 upsample + tree cumsum (merged levels)
    float* F = SMEM;            // 8960
    float* L = SMEM + 8960;     // 8957
    for (int i = tid; i < NSAMP; i += 512) {
        float src = __fsub_rn(__fdiv_rn(__fadd_rn((float)i, 0.5f), 256.0f), 0.5f);
        src = fminf(fmaxf(src, 0.0f), (float)(TT - 1));
        int i0 = (int)floorf(src);
        int i1 = i0 + 1; if (i1 > TT - 1) i1 = TT - 1;
        float w = __fsub_rn(src, (float)i0);
        float a0 = __fmul_rn(f0[b * TT + i0], __fsub_rn(1.0f, w));
        float a1 = __fmul_rn(f0[b * TT + i1], w);
        F[i] = __fadd_rn(a0, a1);
    }
    __syncthreads();
    for (int j = tid; j < 2240; j += 512) {           // levels 1+2
        float a = __fadd_rn(F[4*j],     F[4*j + 1]);
        float c = __fadd_rn(F[4*j + 2], F[4*j + 3]);
        L[LV1 + 2*j] = a; L[LV1 + 2*j + 1] = c;
        L[LV2 + j] = __fadd_rn(a, c);
    }
    __syncthreads();
    for (int j = tid; j < 560; j += 512) {            // levels 3+4
        float a = __fadd_rn(L[LV2 + 4*j],     L[LV2 + 4*j + 1]);
        float c = __fadd_rn(L[LV2 + 4*j + 2], L[LV2 + 4*j + 3]);
        L[LV3 + 2*j] = a; L[LV3 + 2*j + 1] = c;
        L[LV4 + j] = __fadd_rn(a, c);
    }
    __syncthreads();
    if (tid < 140) {                                  // levels 5+6
        int j = tid;
        float a = __fadd_rn(L[LV4 + 4*j],     L[LV4 + 4*j + 1]);
        float c = __fadd_rn(L[LV4 + 4*j + 2], L[LV4 + 4*j + 3]);
        L[LV5 + 2*j] = a; L[LV5 + 2*j + 1] = c;
        L[LV6 + j] = __fadd_rn(a, c);
    }
    __syncthreads();
    if (tid < 35) {                                   // levels 7+8
        int j = tid;
        float a = __fadd_rn(L[LV6 + 4*j],     L[LV6 + 4*j + 1]);
        float c = __fadd_rn(L[LV6 + 4*j + 2], L[LV6 + 4*j + 3]);
        L[LV7 + 2*j] = a; L[LV7 + 2*j + 1] = c;
        L[LV8 + j] = __fadd_rn(a, c);
    }
    __syncthreads();
    if (tid < 9) {                                    // levels 9+10 (L9 has 17 nodes)
        int j = tid;
        if (j < 8) {
            float a = __fadd_rn(L[LV8 + 4*j],     L[LV8 + 4*j + 1]);
            float c = __fadd_rn(L[LV8 + 4*j + 2], L[LV8 + 4*j + 3]);
            L[LV9 + 2*j] = a; L[LV9 + 2*j + 1] = c;
            L[LV10 + j] = __fadd_rn(a, c);
        } else {
            L[LV9 + 16] = __fadd_rn(L[LV8 + 32], L[LV8 + 33]);
        }
    }
    __syncthreads();
    if (tid == 0) {                                   // levels 11..13
        float a0 = __fadd_rn(L[LV10 + 0], L[LV10 + 1]);
        float a1 = __fadd_rn(L[LV10 + 2], L[LV10 + 3]);
        float a2 = __fadd_rn(L[LV10 + 4], L[LV10 + 5]);
        float a3 = __fadd_rn(L[LV10 + 6], L[LV10 + 7]);
        L[LV11 + 0] = a0; L[LV11 + 1] = a1; L[LV11 + 2] = a2; L[LV11 + 3] = a3;
        float b0 = __fadd_rn(a0, a1), b1 = __fadd_rn(a2, a3);
        L[LV12 + 0] = b0; L[LV12 + 1] = b1;
        L[LV13 + 0] = __fadd_rn(b0, b1);
    }
    __syncthreads();
    const int cbase = (fp >= 3) ? (256 * fp - 513) : 0;
    {
        const int offs[14] = {0, LV1, LV2, LV3, LV4, LV5, LV6, LV7, LV8, LV9, LV10, LV11, LV12, LV13};
        for (int w = tid; w < 1281; w += 512) {
            int p = cbase + w;
            if (p < NSAMP) {
                int n = p + 1;
                float acc = 0.f; int pos = 0; bool first = true;
#pragma unroll
                for (int k = 13; k >= 1; --k) {
                    if ((n >> k) & 1) {
                        float t = L[offs[k] + (pos >> k)];
                        acc = first ? t : __fadd_rn(acc, t);
                        first = false;
                        pos += (1 << k);
                    }
                }
                if (n & 1) {
                    float t = F[pos];
                    acc = first ? t : __fadd_rn(acc, t);
                }
                cw[w] = acc;
                fw[w] = F[p];
            }
        }
    }
    __syncthreads();

    // ---- phase 2: FFT pipeline (union reused)
    float* wr_  = SMEM;          // 1024
    float* wi_  = SMEM + 1024;
    float* zfr  = SMEM + 2048;
    float* zfi  = SMEM + 3072;
    float* zgr  = SMEM + 4096;
    float* zgi  = SMEM + 5120;
    float* mpfr = SMEM + 6144;   // 513 each
    float* mpfi = SMEM + 6660;
    float* mpgr = SMEM + 7176;
    float* mpgi = SMEM + 7692;
    const int u = tid & 255;
    const bool lo = (tid < 256);

    {
        const bool gF = (fp > 0) && (pfF0F > 20.0f);
        const bool gG = (pfF0G > 20.0f);
        mpfr[tid] = logf(fmaxf(gF ? pfEpF : 0.0f, 1e-5f));
        mpgr[tid] = logf(fmaxf(gG ? pfEpG : 0.0f, 1e-5f));
        if (tid == 0) {
            mpfr[512] = logf(fmaxf(gF ? pfEpF2 : 0.0f, 1e-5f));
            mpgr[512] = logf(fmaxf(gG ? pfEpG2 : 0.0f, 1e-5f));
        }
    }
    __syncthreads();
#pragma unroll
    for (int r = 0; r < 2; ++r) {
        int n = tid + 512 * r;
        int kv = (n <= 512) ? n : 1024 - n;
        wr_[PHI(n)] = mpfr[kv];
        wi_[PHI(n)] = mpgr[kv];
    }
    dif4(wr_, wi_, twr, twi, -1.f, u, lo);
    const float inv = 1.0f / 1024.0f;
#pragma unroll
    for (int r = 0; r < 2; ++r) {
        int p = tid + 512 * r;
        int n = rev4_10(p);
        float wgt = (n == 0 || n == 512) ? inv : ((n < 512) ? 2.0f * inv : 0.0f);
        wr_[PHI(p)] *= wgt;
        wi_[PHI(p)] *= wgt;
    }
    dit4(wr_, wi_, twr, twi, -1.f, u, lo);      // Y natural
    for (int k = tid; k < BINS; k += 512) {
        int mk = (1024 - k) & 1023;
        float yr = wr_[PHI(k)], yi = wi_[PHI(k)];
        float ymr = wr_[PHI(mk)], ymi = -wi_[PHI(mk)];
        float Lfr = 0.5f * (yr + ymr), Lfi = 0.5f * (yi + ymi);
        float dr = yr - ymr, di = yi - ymi;
        float Lgr = 0.5f * di, Lgi = -0.5f * dr;
        float ef = expf(Lfr);
        mpfr[k] = ef * cosf(Lfi); mpfi[k] = ef * sinf(Lfi);
        float eg = expf(Lgr);
        mpgr[k] = eg * cosf(Lgi); mpgi[k] = eg * sinf(Lgi);
    }
    __syncthreads();
    {
        {
            const int n = tid;
            float v = 0.0f;
            int i = iF0;
            if (i > 0) {
                int iw = i - cbase;
                float ph  = __fdiv_rn(cw[iw], 24000.0f);
                float sw  = __fsub_rn(ph, floorf(ph));
                float ph2 = __fdiv_rn(cw[iw - 1], 24000.0f);
                float sw2 = __fsub_rn(ph2, floorf(ph2));
                if (__fsub_rn(sw, sw2) < 0.0f)
                    v = __fmul_rn(__fdiv_rn(1.0f, __fsqrt_rn(fmaxf(fw[iw], 20.0f))), SQRT_SR);
            }
            zfr[PHI(n)] = __fmul_rn(pfNoiF0, pfWin0);
            zfi[PHI(n)] = __fmul_rn(v, pfWin0);
            float v2 = 0.0f;
            int i2 = iG0;
            if (i2 > 0) {
                int iw = i2 - cbase;
                float ph  = __fdiv_rn(cw[iw], 24000.0f);
                float sw  = __fsub_rn(ph, floorf(ph));
                float ph2 = __fdiv_rn(cw[iw - 1], 24000.0f);
                float sw2 = __fsub_rn(ph2, floorf(ph2));
                if (__fsub_rn(sw, sw2) < 0.0f)
                    v2 = __fmul_rn(__fdiv_rn(1.0f, __fsqrt_rn(fmaxf(fw[iw], 20.0f))), SQRT_SR);
            }
            zgr[PHI(n)] = __fmul_rn(pfNoiG0, pfWin0);
            zgi[PHI(n)] = __fmul_rn(v2, pfWin0);
        }
        {
            const int n = tid + 512;
            float v = 0.0f;
            int i = iF1;
            if (i > 0) {
                int iw = i - cbase;
                float ph  = __fdiv_rn(cw[iw], 24000.0f);
                float sw  = __fsub_rn(ph, floorf(ph));
                float ph2 = __fdiv_rn(cw[iw - 1], 24000.0f);
                float sw2 = __fsub_rn(ph2, floorf(ph2));
                if (__fsub_rn(sw, sw2) < 0.0f)
                    v = __fmul_rn(__fdiv_rn(1.0f, __fsqrt_rn(fmaxf(fw[iw], 20.0f))), SQRT_SR);
            }
            zfr[PHI(n)] = __fmul_rn(pfNoiF1, pfWin1);
            zfi[PHI(n)] = __fmul_rn(v, pfWin1);
            float v2 = 0.0f;
            int i2 = iG1;
            if (i2 > 0) {
                int iw = i2 - cbase;
                float ph  = __fdiv_rn(cw[iw], 24000.0f);
                float sw  = __fsub_rn(ph, floorf(ph));
                float ph2 = __fdiv_rn(cw[iw - 1], 24000.0f);
                float sw2 = __fsub_rn(ph2, floorf(ph2));
                if (__fsub_rn(sw, sw2) < 0.0f)
                    v2 = __fmul_rn(__fdiv_rn(1.0f, __fsqrt_rn(fmaxf(fw[iw], 20.0f))), SQRT_SR);
            }
            zgr[PHI(n)] = __fmul_rn(pfNoiG1, pfWin1);
            zgi[PHI(n)] = __fmul_rn(v2, pfWin1);
        }
    }
    dif4(lo ? zfr : zgr, lo ? zfi : zgi, twr, twi, -1.f, u, true);
    {
        auto vbuild = [&](int p, int kk, float enF, float enG) {
            int k = rev4_10(p);
            bool cj = (k > 512);
            int p1 = rev4_10(kk);
            int p2 = rev4_10((1024 - kk) & 1023);
            float vr, vi;
            {
                float z1r = zfr[PHI(p1)], z1i = zfi[PHI(p1)];
                float z2r = zfr[PHI(p2)], z2i = -zfi[PHI(p2)];
                float Nr = 0.5f * (z1r + z2r), Ni = 0.5f * (z1i + z2i);
                float dr = z1r - z2r, di = z1i - z2i;
                float Ir = 0.5f * di, Ii = -0.5f * dr;
                float mpr = mpfr[kk], mpi2 = mpfi[kk];
                vr = Ir * mpr - Ii * mpi2 + Nr * enF;
                vi = Ir * mpi2 + Ii * mpr + Ni * enF;
                if (cj) vi = -vi;
            }
            float vgr, vgi;
            {
                float z1r = zgr[PHI(p1)], z1i = zgi[PHI(p1)];
                float z2r = zgr[PHI(p2)], z2i = -zgi[PHI(p2)];
                float Nr = 0.5f * (z1r + z2r), Ni = 0.5f * (z1i + z2i);
                float dr = z1r - z2r, di = z1i - z2i;
                float Ir = 0.5f * di, Ii = -0.5f * dr;
                float mpr = mpgr[kk], mpi2 = mpgi[kk];
                vgr = Ir * mpr - Ii * mpi2 + Nr * enG;
                vgi = Ir * mpi2 + Ii * mpr + Ni * enG;
                if (cj) vgi = -vgi;
            }
            wr_[PHI(p)] = vr - vgi;
            wi_[PHI(p)] = vi + vgr;
        };
        vbuild(tid,       kk0, (fp == 0) ? 0.0f : pfEnF0, pfEnG0);
        vbuild(tid + 512, kk1, (fp == 0) ? 0.0f : pfEnF1, pfEnG1);
    }
    dit4(wr_, wi_, twr, twi, +1.f, u, lo);      // natural: 1024*(x_f + i*x_g)
    {
        W[OFF_FR + (((size_t)(b * NFRM + fp)) << 10) + tid]       = __fmul_rn(__fmul_rn(wr_[PHI(tid)], inv), pfWin0);
        W[OFF_FR + (((size_t)(b * NFRM + fg)) << 10) + tid]       = __fmul_rn(__fmul_rn(wi_[PHI(tid)], inv), pfWin0);
        W[OFF_FR + (((size_t)(b * NFRM + fp)) << 10) + tid + 512] = __fmul_rn(__fmul_rn(wr_[PHI(tid + 512)], inv), pfWin1);
        W[OFF_FR + (((size_t)(b * NFRM + fg)) << 10) + tid + 512] = __fmul_rn(__fmul_rn(wi_[PHI(tid + 512)], inv), pfWin1);
    }
}

// swizzled f2 load from a reversed-window array: logical f2 index p,
// physical f2 index phi(p) = p ^ ((p>>4)&15)  (involution, applied on
// both the scatter-write and the read).
__device__ __forceinline__ f2 ldw(const float* A, int p) {
    int ps = p ^ ((p >> 4) & 15);
    return *(const f2*)(A + 2 * ps);
}

// K4 v6 (unchanged from round 10's passing 132.79 version): packed-fp32
// triangular conv + WSQ table.
__global__ __launch_bounds__(256) void k4(const float* __restrict__ rev,
                                          const float* __restrict__ win,
                                          const float* __restrict__ W,
                                          float* __restrict__ out) {
    const int tid = threadIdx.x;
    const int b = blockIdx.x / 72;
    int r = blockIdx.x - b * 72;
    int jt = 0, acc0 = 0;
    while (acc0 + 2 * (jt + 1) <= r) { acc0 += 2 * (jt + 1); ++jt; }
    const int mc = r - acc0;
    const int j0 = jt << 10, m0 = mc << 9;

    __shared__ __align__(16) float TaF[1536];   // T at swizzled f2 positions
    __shared__ __align__(16) float TbF[1536];   // T shifted by 1, swizzled
    __shared__ __align__(16) float RvF[512];
    __shared__ float WSQ[256];

    for (int x = tid; x < 512; x += 256)
        RvF[x] = rev[b * KREV + m0 + x];

    // WSQ[t] = w2(t+768) + w2(t+512) + w2(t+256) + w2(t), in the reference's
    // add order (frames ascending = offsets descending), starting from 0.
    {
        int t = tid;
        float w3v = win[t + 768], w2v = win[t + 512], w1v = win[t + 256], w0v = win[t];
        float wsq = __fadd_rn(0.0f, __fmul_rn(w3v, w3v));
        wsq = __fadd_rn(wsq, __fmul_rn(w2v, w2v));
        wsq = __fadd_rn(wsq, __fmul_rn(w1v, w1v));
        wsq = __fadd_rn(wsq, __fmul_rn(w0v, w0v));
        WSQ[t] = wsq;
    }
    __syncthreads();

    const int base = j0 - m0 - 512;
    for (int x = tid; x < 1536; x += 256) {
        int j = base + x;
        float v = 0.f;
        if (j >= 0 && j < KREV) {
            int s = j + 512;
            if (s >= 1023) {
                int flo = (s - 768) >> 8;
                const float* Wb = W + OFF_FR + (((size_t)(b * NFRM + flo)) << 10);
                int o0 = s - (flo << 8);           // (s&255) + 768
                float acc = __fadd_rn(0.0f, Wb[o0]);
                acc = __fadd_rn(acc, Wb[1024 + o0 - 256]);
                acc = __fadd_rn(acc, Wb[2048 + o0 - 512]);
                acc = __fadd_rn(acc, Wb[3072 + o0 - 768]);
                v = __fdiv_rn(acc, WSQ[s & 255]);
            } else {
                int flo = 0;
                int fhi = s >> 8;
                float acc = 0.f, wsq = 0.f;
                for (int f = flo; f <= fhi; ++f) {
                    int o = s - (f << 8);
                    acc = __fadd_rn(acc, W[OFF_FR + (((size_t)(b * NFRM + f)) << 10) + o]);
                    float wv = win[o];
                    wsq = __fadd_rn(wsq, __fmul_rn(wv, wv));
                }
                float den = (wsq > 1e-11f) ? wsq : 1.0f;
                v = __fdiv_rn(acc, den);
            }
        }
        int t = 1535 - x;                         // T[t] = v
        {
            int pa = t >> 1, ea = t & 1;
            int ps = pa ^ ((pa >> 4) & 15);
            TaF[2 * ps + ea] = v;
        }
        int q = t - 1;                            // TbF[q] = T[q+1] = v
        if (q >= 0) {
            int pb = q >> 1, eb = q & 1;
            int ps = pb ^ ((pb >> 4) & 15);
            TbF[2 * ps + eb] = v;
        }
    }
    __syncthreads();

    const int par = tid & 1;                      // l parity
    const int g = tid >> 1;                       // 0..127
    const float* Tx = par ? TaF : TbF;            // odd l -> Ta, even l -> Tb
    const int B = 511 - 4 * g;                    // B & 3 == 3 always
    const f2* R2 = (const f2*)RvF;

    f2 a0 = (f2){0.f, 0.f}, a1 = a0, a2 = a0, a3 = a0;
    // ring slots by p&3: preload p = B-3 (slot0), B-2 (slot1), B-1 (slot2)
    f2 w0 = ldw(Tx, B - 3);
    f2 w1 = ldw(Tx, B - 2);
    f2 w2 = ldw(Tx, B - 1);
    f2 w3, rc;

    for (int i0 = 0; i0 < 256; i0 += 4) {
        // i = i0+0: new p = B+i0 (slot 3)
        w3 = ldw(Tx, B + i0);     rc = R2[i0];
        PK(a0, rc, w3); PK(a1, rc, w2); PK(a2, rc, w1); PK(a3, rc, w0);
        // i = i0+1: new p = B+i0+1 (slot 0)
        w0 = ldw(Tx, B + i0 + 1); rc = R2[i0 + 1];
        PK(a0, rc, w0); PK(a1, rc, w3); PK(a2, rc, w2); PK(a3, rc, w1);
        // i = i0+2: new p = B+i0+2 (slot 1)
        w1 = ldw(Tx, B + i0 + 2); rc = R2[i0 + 2];
        PK(a0, rc, w1); PK(a1, rc, w0); PK(a2, rc, w3); PK(a3, rc, w2);
        // i = i0+3: new p = B+i0+3 (slot 2)
        w2 = ldw(Tx, B + i0 + 3); rc = R2[i0 + 3];
        PK(a0, rc, w2); PK(a1, rc, w1); PK(a2, rc, w0); PK(a3, rc, w3);
    }

    float* o = out + (size_t)b * LTOT + OUTOFF + j0 + 8 * g + par;
    atomicAdd(o + 0, a0.x + a0.y);
    atomicAdd(o + 2, a1.x + a1.y);
    atomicAdd(o + 4, a2.x + a2.y);
    atomicAdd(o + 6, a3.x + a3.y);
}

extern "C" void kernel_launch(void* const* d_in, const int* in_sizes, int n_in,
                              void* d_out, int out_size, void* d_ws, size_t ws_size,
                              hipStream_t stream) {
    const float* f0      = (const float*)d_in[0];
    const float* env_per = (const float*)d_in[1];
    const float* env_noi = (const float*)d_in[2];
    const float* rev     = (const float*)d_in[3];
    const float* noi     = (const float*)d_in[4];
    const float* win     = (const float*)d_in[5];
    float* out = (float*)d_out;
    float* W   = (float*)d_ws;

    kfrm<<<dim3(136), dim3(512), 0, stream>>>(f0, env_per, env_noi, noi, win, W, out);
    k4<<<dim3(576),   dim3(256), 0, stream>>>(rev, win, W, out);
}